// Round 6
// baseline (174.719 us; speedup 1.0000x reference)
//
#include <hip/hip_runtime.h>
#include <hip/hip_bf16.h>

// Problem constants
#define HEADS   16
#define HD      64
#define DMODEL  1024
#define LQ      2048
#define LK      2048
#define BATCH   4
#define MROWS   8192  // BATCH*LQ

typedef __attribute__((ext_vector_type(8))) short short8;   // 8 bf16 = 4 VGPR
typedef __attribute__((ext_vector_type(4))) float f32x4;    // MFMA 16x16 acc
typedef __attribute__((ext_vector_type(16))) float f32x16;  // MFMA 32x32 acc
typedef __attribute__((ext_vector_type(2))) unsigned int uint2v;

union V4u { unsigned u[4]; short8 s8; };

static __device__ __forceinline__ unsigned short f2bf(float f) {
  unsigned u = __builtin_bit_cast(unsigned, f);
  u = (u + 0x7FFFu + ((u >> 16) & 1u)) >> 16;  // RNE
  return (unsigned short)u;
}

static __device__ __forceinline__ unsigned cvtpk(float lo, float hi) {
  unsigned w;
  asm("v_cvt_pk_bf16_f32 %0, %1, %2" : "=v"(w) : "v"(lo), "v"(hi));
  return w;  // {lo16: bf16(lo), hi16: bf16(hi)}
}

// v_permlane32_swap_b32 vdst, vsrc: swaps vdst's UPPER 32 lanes with vsrc's
// LOWER 32 lanes (verified round 4).
static __device__ __forceinline__ void permswap(unsigned &a, unsigned &b) {
  asm volatile("v_permlane32_swap_b32 %0, %1" : "+v"(a), "+v"(b));
}

static __device__ __forceinline__ void gload_lds16(const void* g, void* l) {
  __builtin_amdgcn_global_load_lds(
      (const __attribute__((address_space(1))) unsigned int*)g,
      (__attribute__((address_space(3))) unsigned int*)l, 16, 0, 0);
}

static __device__ __forceinline__ unsigned lds_addr(const void* p) {
  return (unsigned)(size_t)(const __attribute__((address_space(3))) void*)p;
}

static __device__ __forceinline__ void ds_read128o(unsigned addr, int imm, V4u &d) {
  asm volatile("ds_read_b128 %0, %1 offset:%c2" : "=v"(d.s8) : "v"(addr), "i"(imm));
}

static __device__ __forceinline__ void ds_read_tro(unsigned addr, int imm, uint2v &d) {
  asm volatile("ds_read_b64_tr_b16 %0, %1 offset:%c2" : "=v"(d) : "v"(addr), "i"(imm));
}

// ---------------- fp32 -> bf16 converts (merged launches) ----------------
__global__ void cvt_in_kernel(const float* __restrict__ s0, unsigned short* __restrict__ d0,
                              const float* __restrict__ s1, unsigned short* __restrict__ d1,
                              int n4) {
  int i = blockIdx.x * blockDim.x + threadIdx.x;
  if (i >= n4) return;
  const float* s = blockIdx.y ? s1 : s0;
  unsigned short* d = blockIdx.y ? d1 : d0;
  float4 v = ((const float4*)s)[i];
  ushort4 o;
  o.x = f2bf(v.x); o.y = f2bf(v.y); o.z = f2bf(v.z); o.w = f2bf(v.w);
  ((ushort4*)d)[i] = o;
}

__global__ void cvt_w_kernel(const float* __restrict__ s0, unsigned short* __restrict__ d0,
                             const float* __restrict__ s1, unsigned short* __restrict__ d1,
                             const float* __restrict__ s2, unsigned short* __restrict__ d2,
                             float scale0, int n4) {
  int i = blockIdx.x * blockDim.x + threadIdx.x;
  if (i >= n4) return;
  const float* s = blockIdx.y == 0 ? s0 : (blockIdx.y == 1 ? s1 : s2);
  unsigned short* d = blockIdx.y == 0 ? d0 : (blockIdx.y == 1 ? d1 : d2);
  float sc = blockIdx.y == 0 ? scale0 : 1.0f;
  float4 v = ((const float4*)s)[i];
  ushort4 o;
  o.x = f2bf(v.x * sc); o.y = f2bf(v.y * sc); o.z = f2bf(v.z * sc); o.w = f2bf(v.w * sc);
  ((ushort4*)d)[i] = o;
}

// ---------------- fused QKV GEMM: z selects (A,W,bias,C,bscale) ----------------
__global__ __launch_bounds__(256, 4) void gemm3_kernel(
    const unsigned short* __restrict__ X1,
    const unsigned short* __restrict__ X2,
    const unsigned short* __restrict__ Wqb,
    const unsigned short* __restrict__ Wkb,
    const unsigned short* __restrict__ Wvb,
    const float* __restrict__ bq,
    const float* __restrict__ bk,
    const float* __restrict__ bv,
    unsigned short* __restrict__ Qb,
    unsigned short* __restrict__ Kb,
    unsigned short* __restrict__ Vb,
    float cexp) {
  __shared__ __attribute__((aligned(16))) unsigned short As[128 * 32];
  __shared__ __attribute__((aligned(16))) unsigned short Bs[128 * 32];
  const int sel = blockIdx.z;
  const unsigned short* A = (sel == 0) ? X1 : X2;
  const unsigned short* W = (sel == 0) ? Wqb : (sel == 1) ? Wkb : Wvb;
  const float* bias = (sel == 0) ? bq : (sel == 1) ? bk : bv;
  unsigned short* C = (sel == 0) ? Qb : (sel == 1) ? Kb : Vb;
  const float bscale = (sel == 0) ? cexp : 1.0f;

  const int tid = threadIdx.x;
  const int l = tid & 63, w = tid >> 6;
  const int c = l & 15, g = l >> 4;
  const int wm = w >> 1, wn = w & 1;
  const int m0 = blockIdx.x * 128, n0 = blockIdx.y * 128;

  f32x4 acc[4][4];
#pragma unroll
  for (int i = 0; i < 4; ++i)
#pragma unroll
    for (int j = 0; j < 4; ++j) acc[i][j] = (f32x4){0.f, 0.f, 0.f, 0.f};

  for (int k0 = 0; k0 < 1024; k0 += 32) {
#pragma unroll
    for (int is = 0; is < 2; ++is) {
      int lin = is * 256 + tid;
      int r = lin >> 2, s = lin & 3;
      int gofs = (s ^ (r & 3)) * 8;
      gload_lds16(A + (size_t)(m0 + r) * 1024 + k0 + gofs,
                  &As[(is * 256 + (tid & ~63)) * 8]);
      gload_lds16(W + (size_t)(n0 + r) * 1024 + k0 + gofs,
                  &Bs[(is * 256 + (tid & ~63)) * 8]);
    }
    __syncthreads();
    short8 af[4], bfr[4];
#pragma unroll
    for (int mt = 0; mt < 4; ++mt) {
      int row = wm * 64 + mt * 16 + c;
      af[mt] = *(const short8*)((const char*)As + row * 64 + ((g ^ (row & 3)) << 4));
    }
#pragma unroll
    for (int nt = 0; nt < 4; ++nt) {
      int row = wn * 64 + nt * 16 + c;
      bfr[nt] = *(const short8*)((const char*)Bs + row * 64 + ((g ^ (row & 3)) << 4));
    }
    __builtin_amdgcn_s_setprio(1);
#pragma unroll
    for (int mt = 0; mt < 4; ++mt)
#pragma unroll
      for (int nt = 0; nt < 4; ++nt)
        acc[mt][nt] = __builtin_amdgcn_mfma_f32_16x16x32_bf16(af[mt], bfr[nt], acc[mt][nt], 0, 0, 0);
    __builtin_amdgcn_s_setprio(0);
    __syncthreads();
  }
  float bv4[4];
#pragma unroll
  for (int nt = 0; nt < 4; ++nt) bv4[nt] = bias[n0 + wn * 64 + nt * 16 + c] * bscale;
#pragma unroll
  for (int mt = 0; mt < 4; ++mt)
#pragma unroll
    for (int nt = 0; nt < 4; ++nt)
#pragma unroll
      for (int r = 0; r < 4; ++r) {
        int m = m0 + wm * 64 + mt * 16 + g * 4 + r;
        int n = n0 + wn * 64 + nt * 16 + c;
        C[(size_t)m * 1024 + n] = f2bf(acc[mt][nt][r] + bv4[nt]);
      }
}

// ---------------- fused attention, 4-wave 32x32 swapped-QK^T ----------------
// 256 threads (4 waves), 128 q-rows/block (32/wave), grid 1024 -> 4 blocks/CU.
// Q comes pre-scaled by (1/8)*log2(e). All ds offsets folded into offset: imm.
__global__ __launch_bounds__(256) void attn_kernel(
    const unsigned short* __restrict__ Q,
    const unsigned short* __restrict__ K,
    const unsigned short* __restrict__ V,
    float* __restrict__ out,
    const int* __restrict__ rescale_flag) {
  __shared__ __attribute__((aligned(16))) unsigned short Kbuf[2][64 * 64];
  __shared__ __attribute__((aligned(16))) unsigned short Vbuf[2][64 * 64];
  __shared__ float ivLds[4][32];

  const int tid = threadIdx.x;
  const int lane = tid & 63, w = tid >> 6;      // w in [0,4)
  const int l31 = lane & 31, hi = lane >> 5;

  // XCD-locality remap: 128 consecutive o per XCD -> all 16 q-tiles of a bh
  // land on one XCD (gid%8 = xcd).
  const int gid = blockIdx.x;
  const int xcd = gid & 7;
  const int o = gid >> 3;                        // 0..127
  const int bh = xcd * 8 + (o >> 4);
  const int qb = o & 15;
  const int bb = bh >> 4, h = bh & 15;
  const size_t qrowb = (size_t)bb * LQ + qb * 128 + w * 32;

  const int rs = *rescale_flag;

  // Q fragments (B-operand of swapped QK^T): lane holds Q[q=l31][d=ks*16+hi*8+j]
  short8 qf[4];
#pragma unroll
  for (int ks = 0; ks < 4; ++ks)
    qf[ks] = *(const short8*)(Q + (qrowb + l31) * 1024 + h * 64 + ks * 16 + hi * 8);

  // Staging sources (per-lane). Each thread stages 2 K-slots + 2 V-slots per buffer.
  const size_t kvbase = (size_t)bb * LK * 1024 + (size_t)h * 64;
  // K slot s = r*256+tid: kv = r*32 + (tid>>3), srcslot = (tid&7)^((tid>>3)&7)
  const int k_kv = tid >> 3;
  const int k_sl = (tid & 7) ^ (k_kv & 7);
  const unsigned short* ksrc0 = K + kvbase + (size_t)k_kv * 1024 + k_sl * 8;   // r=0
  const unsigned short* ksrc1 = ksrc0 + (size_t)32 * 1024;                      // r=1 (+32 kv)
  // V slot S = r*256+tid of layout F(kv,d); r=1 adds +32 to d.
  const int v_kv = (w & 3) * 16 + ((lane >> 4) & 1) * 8 + ((lane >> 5) & 1) * 4 + ((lane >> 1) & 3);
  const int v_d  = ((lane >> 3) & 1) * 16 + (lane & 1) * 8;
  const unsigned short* vsrc0 = V + kvbase + (size_t)v_kv * 1024 + v_d;        // r=0
  const unsigned short* vsrc1 = vsrc0 + 32;                                     // r=1 (+32 d)

  // Per-lane K LDS read offsets (byte), constant across tiles/subtiles.
  unsigned koff[4];
#pragma unroll
  for (int ks = 0; ks < 4; ++ks)
    koff[ks] = (unsigned)(l31 * 128 + ((((ks << 1) | hi) ^ (l31 & 7)) << 4));
  const unsigned kbase0 = lds_addr(&Kbuf[0][0]);
  const unsigned vbase0 = lds_addr(&Vbuf[0][0]);

  f32x16 po[2];
  po[0] = {}; po[1] = {};
  float zacc0 = 0.f, zacc1 = 0.f, s2acc0 = 0.f, s2acc1 = 0.f;

  gload_lds16(ksrc0, &Kbuf[0][w * 512]);
  gload_lds16(ksrc1, &Kbuf[0][(4 + w) * 512]);
  gload_lds16(vsrc0, &Vbuf[0][w * 512]);
  gload_lds16(vsrc1, &Vbuf[0][(4 + w) * 512]);
  __syncthreads();

  int cur = 0;
  for (int t = 0; t < LK / 64; ++t) {
    if (t < LK / 64 - 1) {
      const size_t adv = (size_t)(t + 1) * 65536;
      gload_lds16(ksrc0 + adv, &Kbuf[cur ^ 1][w * 512]);
      gload_lds16(ksrc1 + adv, &Kbuf[cur ^ 1][(4 + w) * 512]);
      gload_lds16(vsrc0 + adv, &Vbuf[cur ^ 1][w * 512]);
      gload_lds16(vsrc1 + adv, &Vbuf[cur ^ 1][(4 + w) * 512]);
    }
    unsigned kaddr[4];
#pragma unroll
    for (int ks = 0; ks < 4; ++ks) kaddr[ks] = kbase0 + (unsigned)(cur * 8192) + koff[ks];
    const unsigned vtr = vbase0 + (unsigned)(cur * 8192) + (unsigned)(lane * 8);

#pragma unroll
    for (int s = 0; s < 2; ++s) {
      // ---- issue ALL LDS reads for this subtile (4 K-frags + 8 V tr-reads)
      V4u kfr[4];
#pragma unroll
      for (int ks = 0; ks < 4; ++ks) ds_read128o(kaddr[ks], s * 4096, kfr[ks]);
      uint2v ta0, ta1, ta2, ta3, tb0, tb1, tb2, tb3;
      ds_read_tro(vtr, (2 * s) * 1024, ta0);
      ds_read_tro(vtr, (2 * s) * 1024 + 512, ta1);
      ds_read_tro(vtr, (2 * s) * 1024 + 4096, ta2);
      ds_read_tro(vtr, (2 * s) * 1024 + 4608, ta3);
      ds_read_tro(vtr, (2 * s + 1) * 1024, tb0);
      ds_read_tro(vtr, (2 * s + 1) * 1024 + 512, tb1);
      ds_read_tro(vtr, (2 * s + 1) * 1024 + 4096, tb2);
      ds_read_tro(vtr, (2 * s + 1) * 1024 + 4608, tb3);
      asm volatile("s_waitcnt lgkmcnt(8)" ::: "memory");  // K-frags ready
      __builtin_amdgcn_sched_barrier(0);
      // ---- QK^T (swapped): ps = S^T[kv=crow(r,hi)+32s][q=l31]
      f32x16 ps = {};
      __builtin_amdgcn_s_setprio(1);
#pragma unroll
      for (int ks = 0; ks < 4; ++ks)
        ps = __builtin_amdgcn_mfma_f32_32x32x16_bf16(kfr[ks].s8, qf[ks], ps, 0, 0, 0);
      __builtin_amdgcn_s_setprio(0);
      // ---- softmax piece: lane-local exp; accumulate only what's needed
      float p[16];
#pragma unroll
      for (int r = 0; r < 16; ++r) p[r] = __builtin_amdgcn_exp2f(ps[r]);
      if (rs) {
#pragma unroll
        for (int r = 0; r < 8; ++r) {
          s2acc0 = fmaf(p[2 * r], p[2 * r], s2acc0);
          s2acc1 = fmaf(p[2 * r + 1], p[2 * r + 1], s2acc1);
        }
      } else {
#pragma unroll
        for (int r = 0; r < 8; ++r) {
          zacc0 += p[2 * r];
          zacc1 += p[2 * r + 1];
        }
      }
      // ---- pack P to bf16 words (cvt_pk); wlo[b]={kv 8b+4hi, +1}, whi[b]={+2,+3}
      unsigned wlo[4], whi[4];
#pragma unroll
      for (int b = 0; b < 4; ++b) {
        wlo[b] = cvtpk(p[4 * b + 0], p[4 * b + 1]);
        whi[b] = cvtpk(p[4 * b + 2], p[4 * b + 3]);
      }
      // ---- PV ks=0 (kv4 = 2s): first 4 tr-reads ready at lgkmcnt(4)
      {
        unsigned a0 = wlo[0], b0 = wlo[1];
        unsigned a1 = whi[0], b1 = whi[1];
        permswap(a0, b0);
        permswap(a1, b1);
        V4u pau; pau.u[0] = a0; pau.u[1] = a1; pau.u[2] = b0; pau.u[3] = b1;
        asm volatile("s_waitcnt lgkmcnt(4)" ::: "memory");
        __builtin_amdgcn_sched_barrier(0);
        V4u v0u, v1u;
        v0u.u[0] = ta0[0]; v0u.u[1] = ta0[1]; v0u.u[2] = ta1[0]; v0u.u[3] = ta1[1];
        v1u.u[0] = ta2[0]; v1u.u[1] = ta2[1]; v1u.u[2] = ta3[0]; v1u.u[3] = ta3[1];
        __builtin_amdgcn_s_setprio(1);
        po[0] = __builtin_amdgcn_mfma_f32_32x32x16_bf16(pau.s8, v0u.s8, po[0], 0, 0, 0);
        po[1] = __builtin_amdgcn_mfma_f32_32x32x16_bf16(pau.s8, v1u.s8, po[1], 0, 0, 0);
        __builtin_amdgcn_s_setprio(0);
      }
      // ---- PV ks=1 (kv4 = 2s+1): remaining tr-reads at lgkmcnt(0)
      {
        unsigned a0 = wlo[2], b0 = wlo[3];
        unsigned a1 = whi[2], b1 = whi[3];
        permswap(a0, b0);
        permswap(a1, b1);
        V4u pau; pau.u[0] = a0; pau.u[1] = a1; pau.u[2] = b0; pau.u[3] = b1;
        asm volatile("s_waitcnt lgkmcnt(0)" ::: "memory");
        __builtin_amdgcn_sched_barrier(0);
        V4u v0u, v1u;
        v0u.u[0] = tb0[0]; v0u.u[1] = tb0[1]; v0u.u[2] = tb1[0]; v0u.u[3] = tb1[1];
        v1u.u[0] = tb2[0]; v1u.u[1] = tb2[1]; v1u.u[2] = tb3[0]; v1u.u[3] = tb3[1];
        __builtin_amdgcn_s_setprio(1);
        po[0] = __builtin_amdgcn_mfma_f32_32x32x16_bf16(pau.s8, v0u.s8, po[0], 0, 0, 0);
        po[1] = __builtin_amdgcn_mfma_f32_32x32x16_bf16(pau.s8, v1u.s8, po[1], 0, 0, 0);
        __builtin_amdgcn_s_setprio(0);
      }
    }
    __syncthreads();
    cur ^= 1;
  }

  // ---- denominators: combine the two kv-halves (lane <-> lane+32)
  float zacc = zacc0 + zacc1, s2acc = s2acc0 + s2acc1;
  float z2 = zacc + __shfl_xor(zacc, 32, 64);
  float s22 = s2acc + __shfl_xor(s2acc, 32, 64);
  float iv = rs ? (1.0f / sqrtf(s22)) : (1.0f / z2);
  ivLds[w][l31] = iv;  // both halves write identical value

  // ---- store: O[q=qrowb+crow(r,hi)][d=h*64+dt*32+l31] * iv[q]
#pragma unroll
  for (int dt = 0; dt < 2; ++dt)
#pragma unroll
    for (int r = 0; r < 16; ++r) {
      const int ql = (r & 3) + 8 * (r >> 2) + 4 * hi;
      out[(qrowb + ql) * 1024 + h * 64 + dt * 32 + l31] = po[dt][r] * ivLds[w][ql];
    }
}

extern "C" void kernel_launch(void* const* d_in, const int* in_sizes, int n_in,
                              void* d_out, int out_size, void* d_ws, size_t ws_size,
                              hipStream_t stream) {
  const float* inp1 = (const float*)d_in[0];
  const float* inp2 = (const float*)d_in[1];
  const float* Wq = (const float*)d_in[2];
  const float* bq = (const float*)d_in[3];
  const float* Wk = (const float*)d_in[4];
  const float* bk = (const float*)d_in[5];
  const float* Wv = (const float*)d_in[6];
  const float* bv = (const float*)d_in[7];
  const int* rs = (const int*)d_in[8];
  float* out = (float*)d_out;

  const float CEXP = 0.18033688011112042f;  // (1/8)*log2(e), folded into Wq/bq

  unsigned short* X1  = (unsigned short*)d_ws;              // [8192][1024] bf16
  unsigned short* X2  = X1 + (size_t)MROWS * 1024;
  unsigned short* Wqb = X2 + (size_t)MROWS * 1024;          // [1024][1024] bf16
  unsigned short* Wkb = Wqb + (size_t)1024 * 1024;
  unsigned short* Wvb = Wkb + (size_t)1024 * 1024;
  unsigned short* Qb  = Wvb + (size_t)1024 * 1024;          // [8192][1024] bf16
  unsigned short* Kb  = Qb + (size_t)MROWS * 1024;
  unsigned short* Vb  = Kb + (size_t)MROWS * 1024;

  cvt_in_kernel<<<dim3(MROWS * 1024 / 1024, 2), 256, 0, stream>>>(inp1, X1, inp2, X2, MROWS * 1024 / 4);
  cvt_w_kernel<<<dim3(1024, 3), 256, 0, stream>>>(Wq, Wqb, Wk, Wkb, Wv, Wvb, CEXP, 1024 * 1024 / 4);

  gemm3_kernel<<<dim3(64, 8, 3), 256, 0, stream>>>(X1, X2, Wqb, Wkb, Wvb,
                                                   bq, bk, bv, Qb, Kb, Vb, CEXP);

  attn_kernel<<<dim3(1024), 256, 0, stream>>>(Qb, Kb, Vb, out, rs);
}

// Round 7
// 169.295 us; speedup vs baseline: 1.0320x; 1.0320x over previous
//
#include <hip/hip_runtime.h>
#include <hip/hip_bf16.h>

// Problem constants
#define HEADS   16
#define HD      64
#define DMODEL  1024
#define LQ      2048
#define LK      2048
#define BATCH   4
#define MROWS   8192  // BATCH*LQ

typedef __attribute__((ext_vector_type(8))) short short8;   // 8 bf16 = 4 VGPR
typedef __attribute__((ext_vector_type(4))) float f32x4;    // MFMA 16x16 acc
typedef __attribute__((ext_vector_type(16))) float f32x16;  // MFMA 32x32 acc
typedef __attribute__((ext_vector_type(2))) float f32x2;
typedef __attribute__((ext_vector_type(2))) unsigned int uint2v;

union V4u { unsigned u[4]; short8 s8; };
union PSu { f32x16 v; f32x2 pr[8]; };   // pair view of MFMA acc (consecutive VGPRs)

static __device__ __forceinline__ unsigned short f2bf(float f) {
  unsigned u = __builtin_bit_cast(unsigned, f);
  u = (u + 0x7FFFu + ((u >> 16) & 1u)) >> 16;  // RNE
  return (unsigned short)u;
}

static __device__ __forceinline__ unsigned cvtpk(float lo, float hi) {
  unsigned w;
  asm("v_cvt_pk_bf16_f32 %0, %1, %2" : "=v"(w) : "v"(lo), "v"(hi));
  return w;  // {lo16: bf16(lo), hi16: bf16(hi)}
}

// v_permlane32_swap_b32 vdst, vsrc: swaps vdst's UPPER 32 lanes with vsrc's
// LOWER 32 lanes (verified round 4).
static __device__ __forceinline__ void permswap(unsigned &a, unsigned &b) {
  asm volatile("v_permlane32_swap_b32 %0, %1" : "+v"(a), "+v"(b));
}

// packed f32 (VOP3P): d = a + b
static __device__ __forceinline__ void pk_add(f32x2 &d, f32x2 a, f32x2 b) {
  asm("v_pk_add_f32 %0, %1, %2" : "=v"(d) : "v"(a), "v"(b));
}
// acc += p (packed)
static __device__ __forceinline__ void pk_add_acc(f32x2 &acc, f32x2 p) {
  asm("v_pk_add_f32 %0, %1, %0" : "+v"(acc) : "v"(p));
}
// acc += p*p (packed)
static __device__ __forceinline__ void pk_fma_acc(f32x2 &acc, f32x2 p) {
  asm("v_pk_fma_f32 %0, %1, %1, %0" : "+v"(acc) : "v"(p));
}

static __device__ __forceinline__ void gload_lds16(const void* g, void* l) {
  __builtin_amdgcn_global_load_lds(
      (const __attribute__((address_space(1))) unsigned int*)g,
      (__attribute__((address_space(3))) unsigned int*)l, 16, 0, 0);
}

static __device__ __forceinline__ unsigned lds_addr(const void* p) {
  return (unsigned)(size_t)(const __attribute__((address_space(3))) void*)p;
}

static __device__ __forceinline__ void ds_read128o(unsigned addr, int imm, V4u &d) {
  asm volatile("ds_read_b128 %0, %1 offset:%c2" : "=v"(d.s8) : "v"(addr), "i"(imm));
}

static __device__ __forceinline__ void ds_read_tro(unsigned addr, int imm, uint2v &d) {
  asm volatile("ds_read_b64_tr_b16 %0, %1 offset:%c2" : "=v"(d) : "v"(addr), "i"(imm));
}

// ---------------- fp32 -> bf16 converts (merged launches) ----------------
__global__ void cvt_in_kernel(const float* __restrict__ s0, unsigned short* __restrict__ d0,
                              const float* __restrict__ s1, unsigned short* __restrict__ d1,
                              int n4) {
  int i = blockIdx.x * blockDim.x + threadIdx.x;
  if (i >= n4) return;
  const float* s = blockIdx.y ? s1 : s0;
  unsigned short* d = blockIdx.y ? d1 : d0;
  float4 v = ((const float4*)s)[i];
  ushort4 o;
  o.x = f2bf(v.x); o.y = f2bf(v.y); o.z = f2bf(v.z); o.w = f2bf(v.w);
  ((ushort4*)d)[i] = o;
}

__global__ void cvt_w_kernel(const float* __restrict__ s0, unsigned short* __restrict__ d0,
                             const float* __restrict__ s1, unsigned short* __restrict__ d1,
                             const float* __restrict__ s2, unsigned short* __restrict__ d2,
                             float scale0, int n4) {
  int i = blockIdx.x * blockDim.x + threadIdx.x;
  if (i >= n4) return;
  const float* s = blockIdx.y == 0 ? s0 : (blockIdx.y == 1 ? s1 : s2);
  unsigned short* d = blockIdx.y == 0 ? d0 : (blockIdx.y == 1 ? d1 : d2);
  float sc = blockIdx.y == 0 ? scale0 : 1.0f;
  float4 v = ((const float4*)s)[i];
  ushort4 o;
  o.x = f2bf(v.x * sc); o.y = f2bf(v.y * sc); o.z = f2bf(v.z * sc); o.w = f2bf(v.w * sc);
  ((ushort4*)d)[i] = o;
}

// ---------------- fused QKV GEMM: z selects (A,W,bias,C,bscale) ----------------
__global__ __launch_bounds__(256, 4) void gemm3_kernel(
    const unsigned short* __restrict__ X1,
    const unsigned short* __restrict__ X2,
    const unsigned short* __restrict__ Wqb,
    const unsigned short* __restrict__ Wkb,
    const unsigned short* __restrict__ Wvb,
    const float* __restrict__ bq,
    const float* __restrict__ bk,
    const float* __restrict__ bv,
    unsigned short* __restrict__ Qb,
    unsigned short* __restrict__ Kb,
    unsigned short* __restrict__ Vb,
    float cexp) {
  __shared__ __attribute__((aligned(16))) unsigned short As[128 * 32];
  __shared__ __attribute__((aligned(16))) unsigned short Bs[128 * 32];
  const int sel = blockIdx.z;
  const unsigned short* A = (sel == 0) ? X1 : X2;
  const unsigned short* W = (sel == 0) ? Wqb : (sel == 1) ? Wkb : Wvb;
  const float* bias = (sel == 0) ? bq : (sel == 1) ? bk : bv;
  unsigned short* C = (sel == 0) ? Qb : (sel == 1) ? Kb : Vb;
  const float bscale = (sel == 0) ? cexp : 1.0f;

  const int tid = threadIdx.x;
  const int l = tid & 63, w = tid >> 6;
  const int c = l & 15, g = l >> 4;
  const int wm = w >> 1, wn = w & 1;
  const int m0 = blockIdx.x * 128, n0 = blockIdx.y * 128;

  f32x4 acc[4][4];
#pragma unroll
  for (int i = 0; i < 4; ++i)
#pragma unroll
    for (int j = 0; j < 4; ++j) acc[i][j] = (f32x4){0.f, 0.f, 0.f, 0.f};

  for (int k0 = 0; k0 < 1024; k0 += 32) {
#pragma unroll
    for (int is = 0; is < 2; ++is) {
      int lin = is * 256 + tid;
      int r = lin >> 2, s = lin & 3;
      int gofs = (s ^ (r & 3)) * 8;
      gload_lds16(A + (size_t)(m0 + r) * 1024 + k0 + gofs,
                  &As[(is * 256 + (tid & ~63)) * 8]);
      gload_lds16(W + (size_t)(n0 + r) * 1024 + k0 + gofs,
                  &Bs[(is * 256 + (tid & ~63)) * 8]);
    }
    __syncthreads();
    short8 af[4], bfr[4];
#pragma unroll
    for (int mt = 0; mt < 4; ++mt) {
      int row = wm * 64 + mt * 16 + c;
      af[mt] = *(const short8*)((const char*)As + row * 64 + ((g ^ (row & 3)) << 4));
    }
#pragma unroll
    for (int nt = 0; nt < 4; ++nt) {
      int row = wn * 64 + nt * 16 + c;
      bfr[nt] = *(const short8*)((const char*)Bs + row * 64 + ((g ^ (row & 3)) << 4));
    }
    __builtin_amdgcn_s_setprio(1);
#pragma unroll
    for (int mt = 0; mt < 4; ++mt)
#pragma unroll
      for (int nt = 0; nt < 4; ++nt)
        acc[mt][nt] = __builtin_amdgcn_mfma_f32_16x16x32_bf16(af[mt], bfr[nt], acc[mt][nt], 0, 0, 0);
    __builtin_amdgcn_s_setprio(0);
    __syncthreads();
  }
  float bv4[4];
#pragma unroll
  for (int nt = 0; nt < 4; ++nt) bv4[nt] = bias[n0 + wn * 64 + nt * 16 + c] * bscale;
#pragma unroll
  for (int mt = 0; mt < 4; ++mt)
#pragma unroll
    for (int nt = 0; nt < 4; ++nt)
#pragma unroll
      for (int r = 0; r < 4; ++r) {
        int m = m0 + wm * 64 + mt * 16 + g * 4 + r;
        int n = n0 + wn * 64 + nt * 16 + c;
        C[(size_t)m * 1024 + n] = f2bf(acc[mt][nt][r] + bv4[nt]);
      }
}

// ---------------- fused attention, 8-wave 32x32 swapped-QK^T ----------------
// (round-5 proven structure: 512 threads, 256 q-rows/block, grid 512)
// Q comes pre-scaled by (1/8)*log2(e). Packed-f32 softmax accumulation,
// split QK^T MFMA chains, offset-imm ds reads, counted lgkmcnt waits.
__global__ __launch_bounds__(512) void attn_kernel(
    const unsigned short* __restrict__ Q,
    const unsigned short* __restrict__ K,
    const unsigned short* __restrict__ V,
    float* __restrict__ out,
    const int* __restrict__ rescale_flag) {
  __shared__ __attribute__((aligned(16))) unsigned short Kbuf[2][64 * 64];
  __shared__ __attribute__((aligned(16))) unsigned short Vbuf[2][64 * 64];
  __shared__ float ivLds[8][32];

  const int tid = threadIdx.x;
  const int lane = tid & 63, w = tid >> 6;
  const int l31 = lane & 31, hi = lane >> 5;

  // XCD-locality remap: all 8 q-tiles of one (b,h) on one XCD (gid%8 = xcd).
  const int gid = blockIdx.x;
  const int xcd = gid & 7;
  const int o = gid >> 3;
  const int bh = xcd * 8 + (o >> 3);
  const int qb = o & 7;
  const int bb = bh >> 4, h = bh & 15;
  const size_t qrowb = (size_t)bb * LQ + qb * 256 + w * 32;

  const int rs = *rescale_flag;

  // Q fragments (B-operand of swapped QK^T): lane holds Q[q=l31][d=ks*16+hi*8+j]
  short8 qf[4];
#pragma unroll
  for (int ks = 0; ks < 4; ++ks)
    qf[ks] = *(const short8*)(Q + (qrowb + l31) * 1024 + h * 64 + ks * 16 + hi * 8);

  // Staging source offsets (per-lane, elems within the (b,h) K/V plane).
  const size_t kvbase = (size_t)bb * LK * 1024 + (size_t)h * 64;
  const int k_kv = w * 8 + (lane >> 3);
  const int k_sl = (lane & 7) ^ (lane >> 3);
  const unsigned short* ksrc0 = K + kvbase + (size_t)k_kv * 1024 + k_sl * 8;
  const int v_kv = (w & 3) * 16 + ((lane >> 4) & 1) * 8 + ((lane >> 5) & 1) * 4 + ((lane >> 1) & 3);
  const int v_d  = (w >> 2) * 32 + ((lane >> 3) & 1) * 16 + (lane & 1) * 8;
  const unsigned short* vsrc0 = V + kvbase + (size_t)v_kv * 1024 + v_d;

  // Per-lane K LDS read offsets (byte), constant across tiles/subtiles.
  unsigned koff[4];
#pragma unroll
  for (int ks = 0; ks < 4; ++ks)
    koff[ks] = (unsigned)(l31 * 128 + ((((ks << 1) | hi) ^ (l31 & 7)) << 4));
  const unsigned kbase0 = lds_addr(&Kbuf[0][0]);
  const unsigned vbase0 = lds_addr(&Vbuf[0][0]);

  f32x16 po[2];
  po[0] = {}; po[1] = {};
  f32x2 za[2], s2a[2];
  za[0] = (f32x2){0.f, 0.f}; za[1] = (f32x2){0.f, 0.f};
  s2a[0] = (f32x2){0.f, 0.f}; s2a[1] = (f32x2){0.f, 0.f};

  gload_lds16(ksrc0, &Kbuf[0][w * 512]);
  gload_lds16(vsrc0, &Vbuf[0][w * 512]);
  __syncthreads();

  int cur = 0;
  for (int t = 0; t < LK / 64; ++t) {
    if (t < LK / 64 - 1) {
      gload_lds16(ksrc0 + (size_t)(t + 1) * 65536, &Kbuf[cur ^ 1][w * 512]);
      gload_lds16(vsrc0 + (size_t)(t + 1) * 65536, &Vbuf[cur ^ 1][w * 512]);
    }
    unsigned kaddr[4];
#pragma unroll
    for (int ks = 0; ks < 4; ++ks) kaddr[ks] = kbase0 + (unsigned)(cur * 8192) + koff[ks];
    const unsigned vtr = vbase0 + (unsigned)(cur * 8192) + (unsigned)(lane * 8);

#pragma unroll
    for (int s = 0; s < 2; ++s) {
      // ---- issue ALL LDS reads for this subtile (4 K-frags + 8 V tr-reads)
      V4u kfr[4];
#pragma unroll
      for (int ks = 0; ks < 4; ++ks) ds_read128o(kaddr[ks], s * 4096, kfr[ks]);
      uint2v ta0, ta1, ta2, ta3, tb0, tb1, tb2, tb3;
      ds_read_tro(vtr, (2 * s) * 1024, ta0);
      ds_read_tro(vtr, (2 * s) * 1024 + 512, ta1);
      ds_read_tro(vtr, (2 * s) * 1024 + 4096, ta2);
      ds_read_tro(vtr, (2 * s) * 1024 + 4608, ta3);
      ds_read_tro(vtr, (2 * s + 1) * 1024, tb0);
      ds_read_tro(vtr, (2 * s + 1) * 1024 + 512, tb1);
      ds_read_tro(vtr, (2 * s + 1) * 1024 + 4096, tb2);
      ds_read_tro(vtr, (2 * s + 1) * 1024 + 4608, tb3);
      asm volatile("s_waitcnt lgkmcnt(8)" ::: "memory");  // K-frags ready
      __builtin_amdgcn_sched_barrier(0);
      // ---- QK^T (swapped), two accumulator chains (depth 2 each)
      PSu ps0u, ps1u;
      ps0u.v = (f32x16){};
      ps1u.v = (f32x16){};
      __builtin_amdgcn_s_setprio(1);
      ps0u.v = __builtin_amdgcn_mfma_f32_32x32x16_bf16(kfr[0].s8, qf[0], ps0u.v, 0, 0, 0);
      ps1u.v = __builtin_amdgcn_mfma_f32_32x32x16_bf16(kfr[1].s8, qf[1], ps1u.v, 0, 0, 0);
      ps0u.v = __builtin_amdgcn_mfma_f32_32x32x16_bf16(kfr[2].s8, qf[2], ps0u.v, 0, 0, 0);
      ps1u.v = __builtin_amdgcn_mfma_f32_32x32x16_bf16(kfr[3].s8, qf[3], ps1u.v, 0, 0, 0);
      __builtin_amdgcn_s_setprio(0);
      // ---- merge chains (packed) + exp; accumulate z or s2 (packed)
      f32x2 p2[8];
#pragma unroll
      for (int b = 0; b < 8; ++b) {
        f32x2 tmerge;
        pk_add(tmerge, ps0u.pr[b], ps1u.pr[b]);
        p2[b].x = __builtin_amdgcn_exp2f(tmerge.x);
        p2[b].y = __builtin_amdgcn_exp2f(tmerge.y);
      }
      if (rs) {
#pragma unroll
        for (int b = 0; b < 8; ++b) pk_fma_acc(s2a[b & 1], p2[b]);
      } else {
#pragma unroll
        for (int b = 0; b < 8; ++b) pk_add_acc(za[b & 1], p2[b]);
      }
      // ---- pack P to bf16 words (cvt_pk); wlo[b]={kv 8b+4hi, +1}, whi[b]={+2,+3}
      unsigned wlo[4], whi[4];
#pragma unroll
      for (int b = 0; b < 4; ++b) {
        wlo[b] = cvtpk(p2[2 * b].x, p2[2 * b].y);
        whi[b] = cvtpk(p2[2 * b + 1].x, p2[2 * b + 1].y);
      }
      // ---- PV ks=0 (kv4 = 2s): first 4 tr-reads ready at lgkmcnt(4)
      {
        unsigned a0 = wlo[0], b0 = wlo[1];
        unsigned a1 = whi[0], b1 = whi[1];
        permswap(a0, b0);
        permswap(a1, b1);
        V4u pau; pau.u[0] = a0; pau.u[1] = a1; pau.u[2] = b0; pau.u[3] = b1;
        asm volatile("s_waitcnt lgkmcnt(4)" ::: "memory");
        __builtin_amdgcn_sched_barrier(0);
        V4u v0u, v1u;
        v0u.u[0] = ta0[0]; v0u.u[1] = ta0[1]; v0u.u[2] = ta1[0]; v0u.u[3] = ta1[1];
        v1u.u[0] = ta2[0]; v1u.u[1] = ta2[1]; v1u.u[2] = ta3[0]; v1u.u[3] = ta3[1];
        __builtin_amdgcn_s_setprio(1);
        po[0] = __builtin_amdgcn_mfma_f32_32x32x16_bf16(pau.s8, v0u.s8, po[0], 0, 0, 0);
        po[1] = __builtin_amdgcn_mfma_f32_32x32x16_bf16(pau.s8, v1u.s8, po[1], 0, 0, 0);
        __builtin_amdgcn_s_setprio(0);
      }
      // ---- PV ks=1 (kv4 = 2s+1): remaining tr-reads at lgkmcnt(0)
      {
        unsigned a0 = wlo[2], b0 = wlo[3];
        unsigned a1 = whi[2], b1 = whi[3];
        permswap(a0, b0);
        permswap(a1, b1);
        V4u pau; pau.u[0] = a0; pau.u[1] = a1; pau.u[2] = b0; pau.u[3] = b1;
        asm volatile("s_waitcnt lgkmcnt(0)" ::: "memory");
        __builtin_amdgcn_sched_barrier(0);
        V4u v0u, v1u;
        v0u.u[0] = tb0[0]; v0u.u[1] = tb0[1]; v0u.u[2] = tb1[0]; v0u.u[3] = tb1[1];
        v1u.u[0] = tb2[0]; v1u.u[1] = tb2[1]; v1u.u[2] = tb3[0]; v1u.u[3] = tb3[1];
        __builtin_amdgcn_s_setprio(1);
        po[0] = __builtin_amdgcn_mfma_f32_32x32x16_bf16(pau.s8, v0u.s8, po[0], 0, 0, 0);
        po[1] = __builtin_amdgcn_mfma_f32_32x32x16_bf16(pau.s8, v1u.s8, po[1], 0, 0, 0);
        __builtin_amdgcn_s_setprio(0);
      }
    }
    __syncthreads();
    cur ^= 1;
  }

  // ---- denominators: combine packed accumulators, then the two kv-halves
  float zacc = za[0].x + za[0].y + za[1].x + za[1].y;
  float s2acc = s2a[0].x + s2a[0].y + s2a[1].x + s2a[1].y;
  float z2 = zacc + __shfl_xor(zacc, 32, 64);
  float s22 = s2acc + __shfl_xor(s2acc, 32, 64);
  float iv = rs ? (1.0f / sqrtf(s22)) : (1.0f / z2);
  ivLds[w][l31] = iv;  // both halves write identical value

  // ---- store: O[q=qrowb+crow(r,hi)][d=h*64+dt*32+l31] * iv[q]
#pragma unroll
  for (int dt = 0; dt < 2; ++dt)
#pragma unroll
    for (int r = 0; r < 16; ++r) {
      const int ql = (r & 3) + 8 * (r >> 2) + 4 * hi;
      out[(qrowb + ql) * 1024 + h * 64 + dt * 32 + l31] = po[dt][r] * ivLds[w][ql];
    }
}

extern "C" void kernel_launch(void* const* d_in, const int* in_sizes, int n_in,
                              void* d_out, int out_size, void* d_ws, size_t ws_size,
                              hipStream_t stream) {
  const float* inp1 = (const float*)d_in[0];
  const float* inp2 = (const float*)d_in[1];
  const float* Wq = (const float*)d_in[2];
  const float* bq = (const float*)d_in[3];
  const float* Wk = (const float*)d_in[4];
  const float* bk = (const float*)d_in[5];
  const float* Wv = (const float*)d_in[6];
  const float* bv = (const float*)d_in[7];
  const int* rs = (const int*)d_in[8];
  float* out = (float*)d_out;

  const float CEXP = 0.18033688011112042f;  // (1/8)*log2(e), folded into Wq/bq

  unsigned short* X1  = (unsigned short*)d_ws;              // [8192][1024] bf16
  unsigned short* X2  = X1 + (size_t)MROWS * 1024;
  unsigned short* Wqb = X2 + (size_t)MROWS * 1024;          // [1024][1024] bf16
  unsigned short* Wkb = Wqb + (size_t)1024 * 1024;
  unsigned short* Wvb = Wkb + (size_t)1024 * 1024;
  unsigned short* Qb  = Wvb + (size_t)1024 * 1024;          // [8192][1024] bf16
  unsigned short* Kb  = Qb + (size_t)MROWS * 1024;
  unsigned short* Vb  = Kb + (size_t)MROWS * 1024;

  cvt_in_kernel<<<dim3(MROWS * 1024 / 1024, 2), 256, 0, stream>>>(inp1, X1, inp2, X2, MROWS * 1024 / 4);
  cvt_w_kernel<<<dim3(1024, 3), 256, 0, stream>>>(Wq, Wqb, Wk, Wkb, Wv, Wvb, CEXP, 1024 * 1024 / 4);

  gemm3_kernel<<<dim3(64, 8, 3), 256, 0, stream>>>(X1, X2, Wqb, Wkb, Wvb,
                                                   bq, bk, bv, Qb, Kb, Vb, CEXP);

  attn_kernel<<<dim3(512), 512, 0, stream>>>(Qb, Kb, Vb, out, rs);
}

// Round 8
// 166.478 us; speedup vs baseline: 1.0495x; 1.0169x over previous
//
#include <hip/hip_runtime.h>
#include <hip/hip_bf16.h>

// Problem constants
#define HEADS   16
#define HD      64
#define DMODEL  1024
#define LQ      2048
#define LK      2048
#define BATCH   4
#define MROWS   8192  // BATCH*LQ

typedef __attribute__((ext_vector_type(8))) short short8;   // 8 bf16 = 4 VGPR
typedef __attribute__((ext_vector_type(4))) float f32x4;    // MFMA 16x16 acc
typedef __attribute__((ext_vector_type(16))) float f32x16;  // MFMA 32x32 acc
typedef __attribute__((ext_vector_type(2))) unsigned int uint2v;

union V4u { unsigned u[4]; short8 s8; };

static __device__ __forceinline__ unsigned short f2bf(float f) {
  unsigned u = __builtin_bit_cast(unsigned, f);
  u = (u + 0x7FFFu + ((u >> 16) & 1u)) >> 16;  // RNE
  return (unsigned short)u;
}

static __device__ __forceinline__ unsigned cvtpk(float lo, float hi) {
  unsigned w;
  asm("v_cvt_pk_bf16_f32 %0, %1, %2" : "=v"(w) : "v"(lo), "v"(hi));
  return w;  // {lo16: bf16(lo), hi16: bf16(hi)}
}

// v_permlane32_swap_b32 vdst, vsrc: swaps vdst's UPPER 32 lanes with vsrc's
// LOWER 32 lanes (verified round 4).
static __device__ __forceinline__ void permswap(unsigned &a, unsigned &b) {
  asm volatile("v_permlane32_swap_b32 %0, %1" : "+v"(a), "+v"(b));
}

static __device__ __forceinline__ void gload_lds16(const void* g, void* l) {
  __builtin_amdgcn_global_load_lds(
      (const __attribute__((address_space(1))) unsigned int*)g,
      (__attribute__((address_space(3))) unsigned int*)l, 16, 0, 0);
}

static __device__ __forceinline__ unsigned lds_addr(const void* p) {
  return (unsigned)(size_t)(const __attribute__((address_space(3))) void*)p;
}

static __device__ __forceinline__ void ds_read128o(unsigned addr, int imm, V4u &d) {
  asm volatile("ds_read_b128 %0, %1 offset:%c2" : "=v"(d.s8) : "v"(addr), "i"(imm));
}

static __device__ __forceinline__ void ds_read_tro(unsigned addr, int imm, uint2v &d) {
  asm volatile("ds_read_b64_tr_b16 %0, %1 offset:%c2" : "=v"(d) : "v"(addr), "i"(imm));
}

#define SB() __builtin_amdgcn_sched_barrier(0)

// ---------------- fp32 -> bf16 converts (merged launches) ----------------
__global__ void cvt_in_kernel(const float* __restrict__ s0, unsigned short* __restrict__ d0,
                              const float* __restrict__ s1, unsigned short* __restrict__ d1,
                              int n4) {
  int i = blockIdx.x * blockDim.x + threadIdx.x;
  if (i >= n4) return;
  const float* s = blockIdx.y ? s1 : s0;
  unsigned short* d = blockIdx.y ? d1 : d0;
  float4 v = ((const float4*)s)[i];
  ushort4 o;
  o.x = f2bf(v.x); o.y = f2bf(v.y); o.z = f2bf(v.z); o.w = f2bf(v.w);
  ((ushort4*)d)[i] = o;
}

__global__ void cvt_w_kernel(const float* __restrict__ s0, unsigned short* __restrict__ d0,
                             const float* __restrict__ s1, unsigned short* __restrict__ d1,
                             const float* __restrict__ s2, unsigned short* __restrict__ d2,
                             float scale0, int n4) {
  int i = blockIdx.x * blockDim.x + threadIdx.x;
  if (i >= n4) return;
  const float* s = blockIdx.y == 0 ? s0 : (blockIdx.y == 1 ? s1 : s2);
  unsigned short* d = blockIdx.y == 0 ? d0 : (blockIdx.y == 1 ? d1 : d2);
  float sc = blockIdx.y == 0 ? scale0 : 1.0f;
  float4 v = ((const float4*)s)[i];
  ushort4 o;
  o.x = f2bf(v.x * sc); o.y = f2bf(v.y * sc); o.z = f2bf(v.z * sc); o.w = f2bf(v.w * sc);
  ((ushort4*)d)[i] = o;
}

// ---------------- fused QKV GEMM: z selects (A,W,bias,C,bscale) ----------------
__global__ __launch_bounds__(256, 4) void gemm3_kernel(
    const unsigned short* __restrict__ X1,
    const unsigned short* __restrict__ X2,
    const unsigned short* __restrict__ Wqb,
    const unsigned short* __restrict__ Wkb,
    const unsigned short* __restrict__ Wvb,
    const float* __restrict__ bq,
    const float* __restrict__ bk,
    const float* __restrict__ bv,
    unsigned short* __restrict__ Qb,
    unsigned short* __restrict__ Kb,
    unsigned short* __restrict__ Vb,
    float cexp) {
  __shared__ __attribute__((aligned(16))) unsigned short As[128 * 32];
  __shared__ __attribute__((aligned(16))) unsigned short Bs[128 * 32];
  const int sel = blockIdx.z;
  const unsigned short* A = (sel == 0) ? X1 : X2;
  const unsigned short* W = (sel == 0) ? Wqb : (sel == 1) ? Wkb : Wvb;
  const float* bias = (sel == 0) ? bq : (sel == 1) ? bk : bv;
  unsigned short* C = (sel == 0) ? Qb : (sel == 1) ? Kb : Vb;
  const float bscale = (sel == 0) ? cexp : 1.0f;

  const int tid = threadIdx.x;
  const int l = tid & 63, w = tid >> 6;
  const int c = l & 15, g = l >> 4;
  const int wm = w >> 1, wn = w & 1;
  const int m0 = blockIdx.x * 128, n0 = blockIdx.y * 128;

  f32x4 acc[4][4];
#pragma unroll
  for (int i = 0; i < 4; ++i)
#pragma unroll
    for (int j = 0; j < 4; ++j) acc[i][j] = (f32x4){0.f, 0.f, 0.f, 0.f};

  for (int k0 = 0; k0 < 1024; k0 += 32) {
#pragma unroll
    for (int is = 0; is < 2; ++is) {
      int lin = is * 256 + tid;
      int r = lin >> 2, s = lin & 3;
      int gofs = (s ^ (r & 3)) * 8;
      gload_lds16(A + (size_t)(m0 + r) * 1024 + k0 + gofs,
                  &As[(is * 256 + (tid & ~63)) * 8]);
      gload_lds16(W + (size_t)(n0 + r) * 1024 + k0 + gofs,
                  &Bs[(is * 256 + (tid & ~63)) * 8]);
    }
    __syncthreads();
    short8 af[4], bfr[4];
#pragma unroll
    for (int mt = 0; mt < 4; ++mt) {
      int row = wm * 64 + mt * 16 + c;
      af[mt] = *(const short8*)((const char*)As + row * 64 + ((g ^ (row & 3)) << 4));
    }
#pragma unroll
    for (int nt = 0; nt < 4; ++nt) {
      int row = wn * 64 + nt * 16 + c;
      bfr[nt] = *(const short8*)((const char*)Bs + row * 64 + ((g ^ (row & 3)) << 4));
    }
    __builtin_amdgcn_s_setprio(1);
#pragma unroll
    for (int mt = 0; mt < 4; ++mt)
#pragma unroll
      for (int nt = 0; nt < 4; ++nt)
        acc[mt][nt] = __builtin_amdgcn_mfma_f32_16x16x32_bf16(af[mt], bfr[nt], acc[mt][nt], 0, 0, 0);
    __builtin_amdgcn_s_setprio(0);
    __syncthreads();
  }
  float bv4[4];
#pragma unroll
  for (int nt = 0; nt < 4; ++nt) bv4[nt] = bias[n0 + wn * 64 + nt * 16 + c] * bscale;
#pragma unroll
  for (int mt = 0; mt < 4; ++mt)
#pragma unroll
    for (int nt = 0; nt < 4; ++nt)
#pragma unroll
      for (int r = 0; r < 4; ++r) {
        int m = m0 + wm * 64 + mt * 16 + g * 4 + r;
        int n = n0 + wn * 64 + nt * 16 + c;
        C[(size_t)m * 1024 + n] = f2bf(acc[mt][nt][r] + bv4[nt]);
      }
}

// ---------------- fused attention, 8-wave 32x32 swapped-QK^T ----------------
// Round-5 structure (512 thr, 256 q/block, grid 512) + subtile software
// pipeline: QK(s0),QK(s1) issued before SM(s0) so VALU softmax overlaps MFMA
// execution of the other subtile. Counted lgkmcnt from in-order DS completion.
__global__ __launch_bounds__(512, 4) void attn_kernel(
    const unsigned short* __restrict__ Q,
    const unsigned short* __restrict__ K,
    const unsigned short* __restrict__ V,
    float* __restrict__ out,
    const int* __restrict__ rescale_flag) {
  __shared__ __attribute__((aligned(16))) unsigned short Kbuf[2][64 * 64];
  __shared__ __attribute__((aligned(16))) unsigned short Vbuf[2][64 * 64];
  __shared__ float ivLds[8][32];

  const int tid = threadIdx.x;
  const int lane = tid & 63, w = tid >> 6;
  const int l31 = lane & 31, hi = lane >> 5;

  // XCD-locality remap: all 8 q-tiles of one (b,h) on one XCD (gid%8 = xcd).
  const int gid = blockIdx.x;
  const int xcd = gid & 7;
  const int o = gid >> 3;
  const int bh = xcd * 8 + (o >> 3);
  const int qb = o & 7;
  const int bb = bh >> 4, h = bh & 15;
  const size_t qrowb = (size_t)bb * LQ + qb * 256 + w * 32;

  const int rs = *rescale_flag;

  // Q fragments (B-operand of swapped QK^T): lane holds Q[q=l31][d=ks*16+hi*8+j]
  short8 qf[4];
#pragma unroll
  for (int ks = 0; ks < 4; ++ks)
    qf[ks] = *(const short8*)(Q + (qrowb + l31) * 1024 + h * 64 + ks * 16 + hi * 8);

  // Staging source offsets (per-lane, elems within the (b,h) K/V plane).
  const size_t kvbase = (size_t)bb * LK * 1024 + (size_t)h * 64;
  const int k_kv = w * 8 + (lane >> 3);
  const int k_sl = (lane & 7) ^ (lane >> 3);
  const unsigned short* ksrc0 = K + kvbase + (size_t)k_kv * 1024 + k_sl * 8;
  const int v_kv = (w & 3) * 16 + ((lane >> 4) & 1) * 8 + ((lane >> 5) & 1) * 4 + ((lane >> 1) & 3);
  const int v_d  = (w >> 2) * 32 + ((lane >> 3) & 1) * 16 + (lane & 1) * 8;
  const unsigned short* vsrc0 = V + kvbase + (size_t)v_kv * 1024 + v_d;

  // Per-lane K LDS read offsets (byte), constant across tiles/subtiles.
  unsigned koff[4];
#pragma unroll
  for (int ks = 0; ks < 4; ++ks)
    koff[ks] = (unsigned)(l31 * 128 + ((((ks << 1) | hi) ^ (l31 & 7)) << 4));
  const unsigned kbase0 = lds_addr(&Kbuf[0][0]);
  const unsigned vbase0 = lds_addr(&Vbuf[0][0]);

  f32x16 po[2];
  po[0] = {}; po[1] = {};
  float za0 = 0.f, za1 = 0.f, za2 = 0.f, za3 = 0.f;
  float s20 = 0.f, s21 = 0.f, s22a = 0.f, s23 = 0.f;

  gload_lds16(ksrc0, &Kbuf[0][w * 512]);
  gload_lds16(vsrc0, &Vbuf[0][w * 512]);
  __syncthreads();

  int cur = 0;
  for (int t = 0; t < LK / 64; ++t) {
    if (t < LK / 64 - 1) {
      gload_lds16(ksrc0 + (size_t)(t + 1) * 65536, &Kbuf[cur ^ 1][w * 512]);
      gload_lds16(vsrc0 + (size_t)(t + 1) * 65536, &Vbuf[cur ^ 1][w * 512]);
    }
    unsigned kaddr[4];
#pragma unroll
    for (int ks = 0; ks < 4; ++ks) kaddr[ks] = kbase0 + (unsigned)(cur * 8192) + koff[ks];
    const unsigned vtr = vbase0 + (unsigned)(cur * 8192) + (unsigned)(lane * 8);

    // ---- issue reads: kfr(s0)[4], kfr(s1)[4], trA = V(kv4=0)[4]  (12 in flight)
    V4u kfr0[4], kfr1[4];
#pragma unroll
    for (int ks = 0; ks < 4; ++ks) ds_read128o(kaddr[ks], 0, kfr0[ks]);
#pragma unroll
    for (int ks = 0; ks < 4; ++ks) ds_read128o(kaddr[ks], 4096, kfr1[ks]);
    uint2v ta0, ta1, ta2, ta3, tb0, tb1, tb2, tb3;
    ds_read_tro(vtr, 0, ta0);
    ds_read_tro(vtr, 512, ta1);
    ds_read_tro(vtr, 4096, ta2);
    ds_read_tro(vtr, 4608, ta3);
    asm volatile("s_waitcnt lgkmcnt(8)" ::: "memory");  // kfr0 done
    SB();
    // ---- QK(s0)
    f32x16 ps0 = {};
    __builtin_amdgcn_s_setprio(1);
    ps0 = __builtin_amdgcn_mfma_f32_32x32x16_bf16(kfr0[0].s8, qf[0], ps0, 0, 0, 0);
    ps0 = __builtin_amdgcn_mfma_f32_32x32x16_bf16(kfr0[1].s8, qf[1], ps0, 0, 0, 0);
    ps0 = __builtin_amdgcn_mfma_f32_32x32x16_bf16(kfr0[2].s8, qf[2], ps0, 0, 0, 0);
    ps0 = __builtin_amdgcn_mfma_f32_32x32x16_bf16(kfr0[3].s8, qf[3], ps0, 0, 0, 0);
    __builtin_amdgcn_s_setprio(0);
    SB();
    // ---- issue trB = V(kv4=1)[4]  (<=12 in flight)
    ds_read_tro(vtr, 1024, tb0);
    ds_read_tro(vtr, 1536, tb1);
    ds_read_tro(vtr, 5120, tb2);
    ds_read_tro(vtr, 5632, tb3);
    asm volatile("s_waitcnt lgkmcnt(8)" ::: "memory");  // kfr1 done (16 issued)
    SB();
    // ---- QK(s1) — executes while SM(s0) VALU issues below
    f32x16 ps1 = {};
    __builtin_amdgcn_s_setprio(1);
    ps1 = __builtin_amdgcn_mfma_f32_32x32x16_bf16(kfr1[0].s8, qf[0], ps1, 0, 0, 0);
    ps1 = __builtin_amdgcn_mfma_f32_32x32x16_bf16(kfr1[1].s8, qf[1], ps1, 0, 0, 0);
    ps1 = __builtin_amdgcn_mfma_f32_32x32x16_bf16(kfr1[2].s8, qf[2], ps1, 0, 0, 0);
    ps1 = __builtin_amdgcn_mfma_f32_32x32x16_bf16(kfr1[3].s8, qf[3], ps1, 0, 0, 0);
    __builtin_amdgcn_s_setprio(0);
    SB();
    // ---- SM(s0): exp + accumulate + pack
    {
      float p[16];
#pragma unroll
      for (int r = 0; r < 16; ++r) p[r] = __builtin_amdgcn_exp2f(ps0[r]);
      if (rs) {
#pragma unroll
        for (int r = 0; r < 4; ++r) {
          s20 = fmaf(p[4 * r + 0], p[4 * r + 0], s20);
          s21 = fmaf(p[4 * r + 1], p[4 * r + 1], s21);
          s22a = fmaf(p[4 * r + 2], p[4 * r + 2], s22a);
          s23 = fmaf(p[4 * r + 3], p[4 * r + 3], s23);
        }
      } else {
#pragma unroll
        for (int r = 0; r < 4; ++r) {
          za0 += p[4 * r + 0]; za1 += p[4 * r + 1];
          za2 += p[4 * r + 2]; za3 += p[4 * r + 3];
        }
      }
      unsigned wlo[4], whi[4];
#pragma unroll
      for (int b = 0; b < 4; ++b) {
        wlo[b] = cvtpk(p[4 * b + 0], p[4 * b + 1]);
        whi[b] = cvtpk(p[4 * b + 2], p[4 * b + 3]);
      }
      // PV(s0) ks=0 (uses trA)
      {
        unsigned a0 = wlo[0], b0 = wlo[1], a1 = whi[0], b1 = whi[1];
        permswap(a0, b0); permswap(a1, b1);
        V4u pau; pau.u[0] = a0; pau.u[1] = a1; pau.u[2] = b0; pau.u[3] = b1;
        asm volatile("s_waitcnt lgkmcnt(4)" ::: "memory");  // trA done
        SB();
        V4u v0u, v1u;
        v0u.u[0] = ta0[0]; v0u.u[1] = ta0[1]; v0u.u[2] = ta1[0]; v0u.u[3] = ta1[1];
        v1u.u[0] = ta2[0]; v1u.u[1] = ta2[1]; v1u.u[2] = ta3[0]; v1u.u[3] = ta3[1];
        __builtin_amdgcn_s_setprio(1);
        po[0] = __builtin_amdgcn_mfma_f32_32x32x16_bf16(pau.s8, v0u.s8, po[0], 0, 0, 0);
        po[1] = __builtin_amdgcn_mfma_f32_32x32x16_bf16(pau.s8, v1u.s8, po[1], 0, 0, 0);
        __builtin_amdgcn_s_setprio(0);
      }
      // PV(s0) ks=1 (uses trB)
      {
        unsigned a0 = wlo[2], b0 = wlo[3], a1 = whi[2], b1 = whi[3];
        permswap(a0, b0); permswap(a1, b1);
        V4u pau; pau.u[0] = a0; pau.u[1] = a1; pau.u[2] = b0; pau.u[3] = b1;
        asm volatile("s_waitcnt lgkmcnt(0)" ::: "memory");  // trB done
        SB();
        V4u v0u, v1u;
        v0u.u[0] = tb0[0]; v0u.u[1] = tb0[1]; v0u.u[2] = tb1[0]; v0u.u[3] = tb1[1];
        v1u.u[0] = tb2[0]; v1u.u[1] = tb2[1]; v1u.u[2] = tb3[0]; v1u.u[3] = tb3[1];
        __builtin_amdgcn_s_setprio(1);
        po[0] = __builtin_amdgcn_mfma_f32_32x32x16_bf16(pau.s8, v0u.s8, po[0], 0, 0, 0);
        po[1] = __builtin_amdgcn_mfma_f32_32x32x16_bf16(pau.s8, v1u.s8, po[1], 0, 0, 0);
        __builtin_amdgcn_s_setprio(0);
      }
    }
    // ---- issue trC = V(kv4=2)[4], trD = V(kv4=3)[4]  (8 in flight)
    uint2v tc0, tc1, tc2, tc3, td0, td1, td2, td3;
    ds_read_tro(vtr, 2048, tc0);
    ds_read_tro(vtr, 2560, tc1);
    ds_read_tro(vtr, 6144, tc2);
    ds_read_tro(vtr, 6656, tc3);
    ds_read_tro(vtr, 3072, td0);
    ds_read_tro(vtr, 3584, td1);
    ds_read_tro(vtr, 7168, td2);
    ds_read_tro(vtr, 7680, td3);
    // ---- SM(s1): exp + accumulate + pack (overlaps PV(s0) execution)
    {
      float p[16];
#pragma unroll
      for (int r = 0; r < 16; ++r) p[r] = __builtin_amdgcn_exp2f(ps1[r]);
      if (rs) {
#pragma unroll
        for (int r = 0; r < 4; ++r) {
          s20 = fmaf(p[4 * r + 0], p[4 * r + 0], s20);
          s21 = fmaf(p[4 * r + 1], p[4 * r + 1], s21);
          s22a = fmaf(p[4 * r + 2], p[4 * r + 2], s22a);
          s23 = fmaf(p[4 * r + 3], p[4 * r + 3], s23);
        }
      } else {
#pragma unroll
        for (int r = 0; r < 4; ++r) {
          za0 += p[4 * r + 0]; za1 += p[4 * r + 1];
          za2 += p[4 * r + 2]; za3 += p[4 * r + 3];
        }
      }
      unsigned wlo[4], whi[4];
#pragma unroll
      for (int b = 0; b < 4; ++b) {
        wlo[b] = cvtpk(p[4 * b + 0], p[4 * b + 1]);
        whi[b] = cvtpk(p[4 * b + 2], p[4 * b + 3]);
      }
      // PV(s1) ks=0 (uses trC)
      {
        unsigned a0 = wlo[0], b0 = wlo[1], a1 = whi[0], b1 = whi[1];
        permswap(a0, b0); permswap(a1, b1);
        V4u pau; pau.u[0] = a0; pau.u[1] = a1; pau.u[2] = b0; pau.u[3] = b1;
        asm volatile("s_waitcnt lgkmcnt(4)" ::: "memory");  // trC done
        SB();
        V4u v0u, v1u;
        v0u.u[0] = tc0[0]; v0u.u[1] = tc0[1]; v0u.u[2] = tc1[0]; v0u.u[3] = tc1[1];
        v1u.u[0] = tc2[0]; v1u.u[1] = tc2[1]; v1u.u[2] = tc3[0]; v1u.u[3] = tc3[1];
        __builtin_amdgcn_s_setprio(1);
        po[0] = __builtin_amdgcn_mfma_f32_32x32x16_bf16(pau.s8, v0u.s8, po[0], 0, 0, 0);
        po[1] = __builtin_amdgcn_mfma_f32_32x32x16_bf16(pau.s8, v1u.s8, po[1], 0, 0, 0);
        __builtin_amdgcn_s_setprio(0);
      }
      // PV(s1) ks=1 (uses trD)
      {
        unsigned a0 = wlo[2], b0 = wlo[3], a1 = whi[2], b1 = whi[3];
        permswap(a0, b0); permswap(a1, b1);
        V4u pau; pau.u[0] = a0; pau.u[1] = a1; pau.u[2] = b0; pau.u[3] = b1;
        asm volatile("s_waitcnt lgkmcnt(0)" ::: "memory");  // trD done
        SB();
        V4u v0u, v1u;
        v0u.u[0] = td0[0]; v0u.u[1] = td0[1]; v0u.u[2] = td1[0]; v0u.u[3] = td1[1];
        v1u.u[0] = td2[0]; v1u.u[1] = td2[1]; v1u.u[2] = td3[0]; v1u.u[3] = td3[1];
        __builtin_amdgcn_s_setprio(1);
        po[0] = __builtin_amdgcn_mfma_f32_32x32x16_bf16(pau.s8, v0u.s8, po[0], 0, 0, 0);
        po[1] = __builtin_amdgcn_mfma_f32_32x32x16_bf16(pau.s8, v1u.s8, po[1], 0, 0, 0);
        __builtin_amdgcn_s_setprio(0);
      }
    }
    __syncthreads();
    cur ^= 1;
  }

  // ---- denominators: combine accumulators, then the two kv-halves
  float zacc = (za0 + za1) + (za2 + za3);
  float s2acc = (s20 + s21) + (s22a + s23);
  float z2 = zacc + __shfl_xor(zacc, 32, 64);
  float s22 = s2acc + __shfl_xor(s2acc, 32, 64);
  float iv = rs ? (1.0f / sqrtf(s22)) : (1.0f / z2);
  ivLds[w][l31] = iv;  // both halves write identical value

  // ---- store: O[q=qrowb+crow(r,hi)][d=h*64+dt*32+l31] * iv[q]
#pragma unroll
  for (int dt = 0; dt < 2; ++dt)
#pragma unroll
    for (int r = 0; r < 16; ++r) {
      const int ql = (r & 3) + 8 * (r >> 2) + 4 * hi;
      out[(qrowb + ql) * 1024 + h * 64 + dt * 32 + l31] = po[dt][r] * ivLds[w][ql];
    }
}

extern "C" void kernel_launch(void* const* d_in, const int* in_sizes, int n_in,
                              void* d_out, int out_size, void* d_ws, size_t ws_size,
                              hipStream_t stream) {
  const float* inp1 = (const float*)d_in[0];
  const float* inp2 = (const float*)d_in[1];
  const float* Wq = (const float*)d_in[2];
  const float* bq = (const float*)d_in[3];
  const float* Wk = (const float*)d_in[4];
  const float* bk = (const float*)d_in[5];
  const float* Wv = (const float*)d_in[6];
  const float* bv = (const float*)d_in[7];
  const int* rs = (const int*)d_in[8];
  float* out = (float*)d_out;

  const float CEXP = 0.18033688011112042f;  // (1/8)*log2(e), folded into Wq/bq

  unsigned short* X1  = (unsigned short*)d_ws;              // [8192][1024] bf16
  unsigned short* X2  = X1 + (size_t)MROWS * 1024;
  unsigned short* Wqb = X2 + (size_t)MROWS * 1024;          // [1024][1024] bf16
  unsigned short* Wkb = Wqb + (size_t)1024 * 1024;
  unsigned short* Wvb = Wkb + (size_t)1024 * 1024;
  unsigned short* Qb  = Wvb + (size_t)1024 * 1024;          // [8192][1024] bf16
  unsigned short* Kb  = Qb + (size_t)MROWS * 1024;
  unsigned short* Vb  = Kb + (size_t)MROWS * 1024;

  cvt_in_kernel<<<dim3(MROWS * 1024 / 1024, 2), 256, 0, stream>>>(inp1, X1, inp2, X2, MROWS * 1024 / 4);
  cvt_w_kernel<<<dim3(1024, 3), 256, 0, stream>>>(Wq, Wqb, Wk, Wkb, Wv, Wvb, CEXP, 1024 * 1024 / 4);

  gemm3_kernel<<<dim3(64, 8, 3), 256, 0, stream>>>(X1, X2, Wqb, Wkb, Wvb,
                                                   bq, bk, bv, Qb, Kb, Vb, CEXP);

  attn_kernel<<<dim3(512), 512, 0, stream>>>(Qb, Kb, Vb, out, rs);
}

// Round 9
// 159.482 us; speedup vs baseline: 1.0955x; 1.0439x over previous
//
#include <hip/hip_runtime.h>
#include <hip/hip_bf16.h>

// Problem constants
#define HEADS   16
#define HD      64
#define DMODEL  1024
#define LQ      2048
#define LK      2048
#define BATCH   4
#define MROWS   8192  // BATCH*LQ

typedef __attribute__((ext_vector_type(8))) short short8;   // 8 bf16 = 4 VGPR
typedef __attribute__((ext_vector_type(4))) float f32x4;    // MFMA 16x16 acc
typedef __attribute__((ext_vector_type(16))) float f32x16;  // MFMA 32x32 acc
typedef __attribute__((ext_vector_type(2))) unsigned int uint2v;
typedef __attribute__((ext_vector_type(2))) short bf16x2;

union V4u { unsigned u[4]; short8 s8; };

static __device__ __forceinline__ unsigned short f2bf(float f) {
  unsigned u = __builtin_bit_cast(unsigned, f);
  u = (u + 0x7FFFu + ((u >> 16) & 1u)) >> 16;  // RNE
  return (unsigned short)u;
}

static __device__ __forceinline__ unsigned cvtpk(float lo, float hi) {
  unsigned w;
  asm("v_cvt_pk_bf16_f32 %0, %1, %2" : "=v"(w) : "v"(lo), "v"(hi));
  return w;  // {lo16: bf16(lo), hi16: bf16(hi)}
}

// v_permlane32_swap_b32 vdst, vsrc: swaps vdst's UPPER 32 lanes with vsrc's
// LOWER 32 lanes (verified round 4).
static __device__ __forceinline__ void permswap(unsigned &a, unsigned &b) {
  asm volatile("v_permlane32_swap_b32 %0, %1" : "+v"(a), "+v"(b));
}

static __device__ __forceinline__ void gload_lds16(const void* g, void* l) {
  __builtin_amdgcn_global_load_lds(
      (const __attribute__((address_space(1))) unsigned int*)g,
      (__attribute__((address_space(3))) unsigned int*)l, 16, 0, 0);
}

static __device__ __forceinline__ unsigned lds_addr(const void* p) {
  return (unsigned)(size_t)(const __attribute__((address_space(3))) void*)p;
}

static __device__ __forceinline__ void ds_read128o(unsigned addr, int imm, V4u &d) {
  asm volatile("ds_read_b128 %0, %1 offset:%c2" : "=v"(d.s8) : "v"(addr), "i"(imm));
}

static __device__ __forceinline__ void ds_read_tro(unsigned addr, int imm, uint2v &d) {
  asm volatile("ds_read_b64_tr_b16 %0, %1 offset:%c2" : "=v"(d) : "v"(addr), "i"(imm));
}

// s2 += dot2(w, w), z += dot2(w, {1,1}) using bf16 dot if available.
#if __has_builtin(__builtin_amdgcn_fdot2_f32_bf16)
#define HAVE_BF16_DOT2 1
static __device__ __forceinline__ float dot2_sq(unsigned w, float acc) {
  bf16x2 v = __builtin_bit_cast(bf16x2, w);
  return __builtin_amdgcn_fdot2_f32_bf16(v, v, acc, false);
}
static __device__ __forceinline__ float dot2_sum(unsigned w, float acc) {
  bf16x2 ones = __builtin_bit_cast(bf16x2, 0x3F803F80u);  // {1.0bf, 1.0bf}
  bf16x2 v = __builtin_bit_cast(bf16x2, w);
  return __builtin_amdgcn_fdot2_f32_bf16(v, ones, acc, false);
}
#else
#define HAVE_BF16_DOT2 0
#endif

// ---------------- fp32 -> bf16 converts (merged launches) ----------------
__global__ void cvt_in_kernel(const float* __restrict__ s0, unsigned short* __restrict__ d0,
                              const float* __restrict__ s1, unsigned short* __restrict__ d1,
                              int n4) {
  int i = blockIdx.x * blockDim.x + threadIdx.x;
  if (i >= n4) return;
  const float* s = blockIdx.y ? s1 : s0;
  unsigned short* d = blockIdx.y ? d1 : d0;
  float4 v = ((const float4*)s)[i];
  ushort4 o;
  o.x = f2bf(v.x); o.y = f2bf(v.y); o.z = f2bf(v.z); o.w = f2bf(v.w);
  ((ushort4*)d)[i] = o;
}

__global__ void cvt_w_kernel(const float* __restrict__ s0, unsigned short* __restrict__ d0,
                             const float* __restrict__ s1, unsigned short* __restrict__ d1,
                             const float* __restrict__ s2, unsigned short* __restrict__ d2,
                             float scale0, int n4) {
  int i = blockIdx.x * blockDim.x + threadIdx.x;
  if (i >= n4) return;
  const float* s = blockIdx.y == 0 ? s0 : (blockIdx.y == 1 ? s1 : s2);
  unsigned short* d = blockIdx.y == 0 ? d0 : (blockIdx.y == 1 ? d1 : d2);
  float sc = blockIdx.y == 0 ? scale0 : 1.0f;
  float4 v = ((const float4*)s)[i];
  ushort4 o;
  o.x = f2bf(v.x * sc); o.y = f2bf(v.y * sc); o.z = f2bf(v.z * sc); o.w = f2bf(v.w * sc);
  ((ushort4*)d)[i] = o;
}

// ---------------- fused QKV GEMM: z selects (A,W,bias,C,bscale) ----------------
__global__ __launch_bounds__(256, 4) void gemm3_kernel(
    const unsigned short* __restrict__ X1,
    const unsigned short* __restrict__ X2,
    const unsigned short* __restrict__ Wqb,
    const unsigned short* __restrict__ Wkb,
    const unsigned short* __restrict__ Wvb,
    const float* __restrict__ bq,
    const float* __restrict__ bk,
    const float* __restrict__ bv,
    unsigned short* __restrict__ Qb,
    unsigned short* __restrict__ Kb,
    unsigned short* __restrict__ Vb,
    float cexp) {
  __shared__ __attribute__((aligned(16))) unsigned short As[128 * 32];
  __shared__ __attribute__((aligned(16))) unsigned short Bs[128 * 32];
  const int sel = blockIdx.z;
  const unsigned short* A = (sel == 0) ? X1 : X2;
  const unsigned short* W = (sel == 0) ? Wqb : (sel == 1) ? Wkb : Wvb;
  const float* bias = (sel == 0) ? bq : (sel == 1) ? bk : bv;
  unsigned short* C = (sel == 0) ? Qb : (sel == 1) ? Kb : Vb;
  const float bscale = (sel == 0) ? cexp : 1.0f;

  const int tid = threadIdx.x;
  const int l = tid & 63, w = tid >> 6;
  const int c = l & 15, g = l >> 4;
  const int wm = w >> 1, wn = w & 1;
  const int m0 = blockIdx.x * 128, n0 = blockIdx.y * 128;

  f32x4 acc[4][4];
#pragma unroll
  for (int i = 0; i < 4; ++i)
#pragma unroll
    for (int j = 0; j < 4; ++j) acc[i][j] = (f32x4){0.f, 0.f, 0.f, 0.f};

  for (int k0 = 0; k0 < 1024; k0 += 32) {
#pragma unroll
    for (int is = 0; is < 2; ++is) {
      int lin = is * 256 + tid;
      int r = lin >> 2, s = lin & 3;
      int gofs = (s ^ (r & 3)) * 8;
      gload_lds16(A + (size_t)(m0 + r) * 1024 + k0 + gofs,
                  &As[(is * 256 + (tid & ~63)) * 8]);
      gload_lds16(W + (size_t)(n0 + r) * 1024 + k0 + gofs,
                  &Bs[(is * 256 + (tid & ~63)) * 8]);
    }
    __syncthreads();
    short8 af[4], bfr[4];
#pragma unroll
    for (int mt = 0; mt < 4; ++mt) {
      int row = wm * 64 + mt * 16 + c;
      af[mt] = *(const short8*)((const char*)As + row * 64 + ((g ^ (row & 3)) << 4));
    }
#pragma unroll
    for (int nt = 0; nt < 4; ++nt) {
      int row = wn * 64 + nt * 16 + c;
      bfr[nt] = *(const short8*)((const char*)Bs + row * 64 + ((g ^ (row & 3)) << 4));
    }
    __builtin_amdgcn_s_setprio(1);
#pragma unroll
    for (int mt = 0; mt < 4; ++mt)
#pragma unroll
      for (int nt = 0; nt < 4; ++nt)
        acc[mt][nt] = __builtin_amdgcn_mfma_f32_16x16x32_bf16(af[mt], bfr[nt], acc[mt][nt], 0, 0, 0);
    __builtin_amdgcn_s_setprio(0);
    __syncthreads();
  }
  float bv4[4];
#pragma unroll
  for (int nt = 0; nt < 4; ++nt) bv4[nt] = bias[n0 + wn * 64 + nt * 16 + c] * bscale;
#pragma unroll
  for (int mt = 0; mt < 4; ++mt)
#pragma unroll
    for (int nt = 0; nt < 4; ++nt)
#pragma unroll
      for (int r = 0; r < 4; ++r) {
        int m = m0 + wm * 64 + mt * 16 + g * 4 + r;
        int n = n0 + wn * 64 + nt * 16 + c;
        C[(size_t)m * 1024 + n] = f2bf(acc[mt][nt][r] + bv4[nt]);
      }
}

// ---------------- fused attention, 8-wave 32x32 swapped-QK^T ----------------
// Round-5 proven structure: 512 threads, 256 q-rows/block, grid 512, simple
// 2-barrier K-tile loop, all LDS reads issued up-front with counted lgkmcnt.
// Only change vs r5: z/s2 accumulation via v_dot2_f32_bf16 on the packed P
// words (8 dot2 replace 16 scalar fma/add), placed after the pack so it sits
// off the exp->pack->PV critical path.
__global__ __launch_bounds__(512) void attn_kernel(
    const unsigned short* __restrict__ Q,
    const unsigned short* __restrict__ K,
    const unsigned short* __restrict__ V,
    float* __restrict__ out,
    const int* __restrict__ rescale_flag) {
  __shared__ __attribute__((aligned(16))) unsigned short Kbuf[2][64 * 64];
  __shared__ __attribute__((aligned(16))) unsigned short Vbuf[2][64 * 64];
  __shared__ float ivLds[8][32];

  const int tid = threadIdx.x;
  const int lane = tid & 63, w = tid >> 6;
  const int l31 = lane & 31, hi = lane >> 5;

  // XCD-locality remap: all 8 q-tiles of one (b,h) on one XCD (gid%8 = xcd).
  const int gid = blockIdx.x;
  const int xcd = gid & 7;
  const int o = gid >> 3;
  const int bh = xcd * 8 + (o >> 3);
  const int qb = o & 7;
  const int bb = bh >> 4, h = bh & 15;
  const size_t qrowb = (size_t)bb * LQ + qb * 256 + w * 32;

  const int rs = *rescale_flag;

  // Q fragments (B-operand of swapped QK^T): lane holds Q[q=l31][d=ks*16+hi*8+j]
  short8 qf[4];
#pragma unroll
  for (int ks = 0; ks < 4; ++ks)
    qf[ks] = *(const short8*)(Q + (qrowb + l31) * 1024 + h * 64 + ks * 16 + hi * 8);

  // Staging source offsets (per-lane, elems within the (b,h) K/V plane).
  const size_t kvbase = (size_t)bb * LK * 1024 + (size_t)h * 64;
  const int k_kv = w * 8 + (lane >> 3);
  const int k_sl = (lane & 7) ^ (lane >> 3);
  const unsigned short* ksrc0 = K + kvbase + (size_t)k_kv * 1024 + k_sl * 8;
  const int v_kv = (w & 3) * 16 + ((lane >> 4) & 1) * 8 + ((lane >> 5) & 1) * 4 + ((lane >> 1) & 3);
  const int v_d  = (w >> 2) * 32 + ((lane >> 3) & 1) * 16 + (lane & 1) * 8;
  const unsigned short* vsrc0 = V + kvbase + (size_t)v_kv * 1024 + v_d;

  // Per-lane K LDS read offsets (byte), constant across tiles/subtiles.
  unsigned koff[4];
#pragma unroll
  for (int ks = 0; ks < 4; ++ks)
    koff[ks] = (unsigned)(l31 * 128 + ((((ks << 1) | hi) ^ (l31 & 7)) << 4));
  const unsigned kbase0 = lds_addr(&Kbuf[0][0]);
  const unsigned vbase0 = lds_addr(&Vbuf[0][0]);

  f32x16 po[2];
  po[0] = {}; po[1] = {};
  float za0 = 0.f, za1 = 0.f, s20 = 0.f, s21 = 0.f;

  gload_lds16(ksrc0, &Kbuf[0][w * 512]);
  gload_lds16(vsrc0, &Vbuf[0][w * 512]);
  __syncthreads();

  int cur = 0;
  for (int t = 0; t < LK / 64; ++t) {
    if (t < LK / 64 - 1) {
      gload_lds16(ksrc0 + (size_t)(t + 1) * 65536, &Kbuf[cur ^ 1][w * 512]);
      gload_lds16(vsrc0 + (size_t)(t + 1) * 65536, &Vbuf[cur ^ 1][w * 512]);
    }
    unsigned kaddr[4];
#pragma unroll
    for (int ks = 0; ks < 4; ++ks) kaddr[ks] = kbase0 + (unsigned)(cur * 8192) + koff[ks];
    const unsigned vtr = vbase0 + (unsigned)(cur * 8192) + (unsigned)(lane * 8);

#pragma unroll
    for (int s = 0; s < 2; ++s) {
      // ---- issue ALL LDS reads for this subtile (4 K-frags + 8 V tr-reads)
      V4u kfr[4];
#pragma unroll
      for (int ks = 0; ks < 4; ++ks) ds_read128o(kaddr[ks], s * 4096, kfr[ks]);
      uint2v ta0, ta1, ta2, ta3, tb0, tb1, tb2, tb3;
      ds_read_tro(vtr, (2 * s) * 1024, ta0);
      ds_read_tro(vtr, (2 * s) * 1024 + 512, ta1);
      ds_read_tro(vtr, (2 * s) * 1024 + 4096, ta2);
      ds_read_tro(vtr, (2 * s) * 1024 + 4608, ta3);
      ds_read_tro(vtr, (2 * s + 1) * 1024, tb0);
      ds_read_tro(vtr, (2 * s + 1) * 1024 + 512, tb1);
      ds_read_tro(vtr, (2 * s + 1) * 1024 + 4096, tb2);
      ds_read_tro(vtr, (2 * s + 1) * 1024 + 4608, tb3);
      asm volatile("s_waitcnt lgkmcnt(8)" ::: "memory");  // K-frags ready
      __builtin_amdgcn_sched_barrier(0);
      // ---- QK^T (swapped): ps = S^T[kv=crow(r,hi)+32s][q=l31]
      f32x16 ps = {};
      __builtin_amdgcn_s_setprio(1);
      ps = __builtin_amdgcn_mfma_f32_32x32x16_bf16(kfr[0].s8, qf[0], ps, 0, 0, 0);
      ps = __builtin_amdgcn_mfma_f32_32x32x16_bf16(kfr[1].s8, qf[1], ps, 0, 0, 0);
      ps = __builtin_amdgcn_mfma_f32_32x32x16_bf16(kfr[2].s8, qf[2], ps, 0, 0, 0);
      ps = __builtin_amdgcn_mfma_f32_32x32x16_bf16(kfr[3].s8, qf[3], ps, 0, 0, 0);
      __builtin_amdgcn_s_setprio(0);
      // ---- softmax piece: lane-local exp
      float p[16];
#pragma unroll
      for (int r = 0; r < 16; ++r) p[r] = __builtin_amdgcn_exp2f(ps[r]);
      // ---- pack P to bf16 words (cvt_pk); wlo[b]={kv 8b+4hi, +1}, whi[b]={+2,+3}
      unsigned wlo[4], whi[4];
#pragma unroll
      for (int b = 0; b < 4; ++b) {
        wlo[b] = cvtpk(p[4 * b + 0], p[4 * b + 1]);
        whi[b] = cvtpk(p[4 * b + 2], p[4 * b + 3]);
      }
      // ---- accumulate z or s2 from packed words (off the PV critical path)
#if HAVE_BF16_DOT2
      if (rs) {
#pragma unroll
        for (int b = 0; b < 4; ++b) {
          s20 = dot2_sq(wlo[b], s20);
          s21 = dot2_sq(whi[b], s21);
        }
      } else {
#pragma unroll
        for (int b = 0; b < 4; ++b) {
          za0 = dot2_sum(wlo[b], za0);
          za1 = dot2_sum(whi[b], za1);
        }
      }
#else
      if (rs) {
#pragma unroll
        for (int r = 0; r < 8; ++r) {
          s20 = fmaf(p[2 * r], p[2 * r], s20);
          s21 = fmaf(p[2 * r + 1], p[2 * r + 1], s21);
        }
      } else {
#pragma unroll
        for (int r = 0; r < 8; ++r) {
          za0 += p[2 * r];
          za1 += p[2 * r + 1];
        }
      }
#endif
      // ---- PV ks=0 (kv4 = 2s): first 4 tr-reads ready at lgkmcnt(4)
      {
        unsigned a0 = wlo[0], b0 = wlo[1], a1 = whi[0], b1 = whi[1];
        permswap(a0, b0);
        permswap(a1, b1);
        V4u pau; pau.u[0] = a0; pau.u[1] = a1; pau.u[2] = b0; pau.u[3] = b1;
        asm volatile("s_waitcnt lgkmcnt(4)" ::: "memory");
        __builtin_amdgcn_sched_barrier(0);
        V4u v0u, v1u;
        v0u.u[0] = ta0[0]; v0u.u[1] = ta0[1]; v0u.u[2] = ta1[0]; v0u.u[3] = ta1[1];
        v1u.u[0] = ta2[0]; v1u.u[1] = ta2[1]; v1u.u[2] = ta3[0]; v1u.u[3] = ta3[1];
        __builtin_amdgcn_s_setprio(1);
        po[0] = __builtin_amdgcn_mfma_f32_32x32x16_bf16(pau.s8, v0u.s8, po[0], 0, 0, 0);
        po[1] = __builtin_amdgcn_mfma_f32_32x32x16_bf16(pau.s8, v1u.s8, po[1], 0, 0, 0);
        __builtin_amdgcn_s_setprio(0);
      }
      // ---- PV ks=1 (kv4 = 2s+1): remaining tr-reads at lgkmcnt(0)
      {
        unsigned a0 = wlo[2], b0 = wlo[3], a1 = whi[2], b1 = whi[3];
        permswap(a0, b0);
        permswap(a1, b1);
        V4u pau; pau.u[0] = a0; pau.u[1] = a1; pau.u[2] = b0; pau.u[3] = b1;
        asm volatile("s_waitcnt lgkmcnt(0)" ::: "memory");
        __builtin_amdgcn_sched_barrier(0);
        V4u v0u, v1u;
        v0u.u[0] = tb0[0]; v0u.u[1] = tb0[1]; v0u.u[2] = tb1[0]; v0u.u[3] = tb1[1];
        v1u.u[0] = tb2[0]; v1u.u[1] = tb2[1]; v1u.u[2] = tb3[0]; v1u.u[3] = tb3[1];
        __builtin_amdgcn_s_setprio(1);
        po[0] = __builtin_amdgcn_mfma_f32_32x32x16_bf16(pau.s8, v0u.s8, po[0], 0, 0, 0);
        po[1] = __builtin_amdgcn_mfma_f32_32x32x16_bf16(pau.s8, v1u.s8, po[1], 0, 0, 0);
        __builtin_amdgcn_s_setprio(0);
      }
    }
    __syncthreads();
    cur ^= 1;
  }

  // ---- denominators: combine accumulators, then the two kv-halves
  float zacc = za0 + za1;
  float s2acc = s20 + s21;
  float z2 = zacc + __shfl_xor(zacc, 32, 64);
  float s22 = s2acc + __shfl_xor(s2acc, 32, 64);
  float iv = rs ? (1.0f / sqrtf(s22)) : (1.0f / z2);
  ivLds[w][l31] = iv;  // both halves write identical value

  // ---- store: O[q=qrowb+crow(r,hi)][d=h*64+dt*32+l31] * iv[q]
#pragma unroll
  for (int dt = 0; dt < 2; ++dt)
#pragma unroll
    for (int r = 0; r < 16; ++r) {
      const int ql = (r & 3) + 8 * (r >> 2) + 4 * hi;
      out[(qrowb + ql) * 1024 + h * 64 + dt * 32 + l31] = po[dt][r] * ivLds[w][ql];
    }
}

extern "C" void kernel_launch(void* const* d_in, const int* in_sizes, int n_in,
                              void* d_out, int out_size, void* d_ws, size_t ws_size,
                              hipStream_t stream) {
  const float* inp1 = (const float*)d_in[0];
  const float* inp2 = (const float*)d_in[1];
  const float* Wq = (const float*)d_in[2];
  const float* bq = (const float*)d_in[3];
  const float* Wk = (const float*)d_in[4];
  const float* bk = (const float*)d_in[5];
  const float* Wv = (const float*)d_in[6];
  const float* bv = (const float*)d_in[7];
  const int* rs = (const int*)d_in[8];
  float* out = (float*)d_out;

  const float CEXP = 0.18033688011112042f;  // (1/8)*log2(e), folded into Wq/bq

  unsigned short* X1  = (unsigned short*)d_ws;              // [8192][1024] bf16
  unsigned short* X2  = X1 + (size_t)MROWS * 1024;
  unsigned short* Wqb = X2 + (size_t)MROWS * 1024;          // [1024][1024] bf16
  unsigned short* Wkb = Wqb + (size_t)1024 * 1024;
  unsigned short* Wvb = Wkb + (size_t)1024 * 1024;
  unsigned short* Qb  = Wvb + (size_t)1024 * 1024;          // [8192][1024] bf16
  unsigned short* Kb  = Qb + (size_t)MROWS * 1024;
  unsigned short* Vb  = Kb + (size_t)MROWS * 1024;

  cvt_in_kernel<<<dim3(MROWS * 1024 / 1024, 2), 256, 0, stream>>>(inp1, X1, inp2, X2, MROWS * 1024 / 4);
  cvt_w_kernel<<<dim3(1024, 3), 256, 0, stream>>>(Wq, Wqb, Wk, Wkb, Wv, Wvb, CEXP, 1024 * 1024 / 4);

  gemm3_kernel<<<dim3(64, 8, 3), 256, 0, stream>>>(X1, X2, Wqb, Wkb, Wvb,
                                                   bq, bk, bv, Qb, Kb, Vb, CEXP);

  attn_kernel<<<dim3(512), 512, 0, stream>>>(Qb, Kb, Vb, out, rs);
}